// Round 3
// baseline (599.658 us; speedup 1.0000x reference)
//
#include <hip/hip_runtime.h>
#include <hip/hip_bf16.h>
#include <cstdint>
#include <cstddef>

// MultiHeadAttention: B=4, S=2048, D=1024, H=16, dk=64.
// Inputs fp32, output fp32 (reference dtypes). Internals bf16 MFMA.
// Pipeline: 3x gemm (QKV proj fp32->bf16 ws [B,H,S,dk]) -> flash attn (bf16) -> out proj (bf16 in, fp32 out).

#define BATCH   4
#define SEQ     2048
#define D_MODEL 1024
#define NHEADS  16
#define DK      64

typedef __attribute__((ext_vector_type(8))) __bf16 bf16x8_t;
typedef __attribute__((ext_vector_type(4))) __bf16 bf16x4_t;
typedef __attribute__((ext_vector_type(4))) float  f32x4;

__device__ inline unsigned short f2bf(float f) {
  union { float f; unsigned int i; } c; c.f = f;
  unsigned int i = c.i;
  i += 0x7FFFu + ((i >> 16) & 1u);   // RNE
  return (unsigned short)(i >> 16);
}
__device__ inline unsigned int pack2(float lo, float hi) {
  return ((unsigned int)f2bf(lo)) | (((unsigned int)f2bf(hi)) << 16);
}
// load 8 fp32, convert RNE, store 8 bf16 (16B) to LDS
__device__ inline void cvt8_store(const float* __restrict__ src, unsigned short* dst) {
  const float4 a = *(const float4*)(src);
  const float4 b = *(const float4*)(src + 4);
  uint4 r;
  r.x = pack2(a.x, a.y); r.y = pack2(a.z, a.w);
  r.z = pack2(b.x, b.y); r.w = pack2(b.z, b.w);
  *(uint4*)dst = r;
}

__device__ inline bf16x8_t lds_frag(const unsigned short* p) {
  return *(const bf16x8_t*)p;
}

// C[m][n] = sum_k A[m][k] * W[n][k] + bias[n]   (nn.Linear, W row-major [N][K], fp32)
// A_IS_BF16: A is bf16 workspace else fp32. OUT_QKV: scatter into [B,H,S,dk] bf16.
// OUT_F32: write fp32 row-major (final output) else bf16.
template <int OUT_QKV, int A_IS_BF16, int OUT_F32>
__global__ __launch_bounds__(256) void gemm_bt_kernel(
    const void* __restrict__ Av,
    const float* __restrict__ W,
    const float* __restrict__ bias,
    void* __restrict__ Cv,
    int M, int N, int Kd)
{
  // stride 40 bf16 = 80B: 16B-aligned fragments, bank advance 20 -> 2-way (free)
  __shared__ unsigned short a_lds[128 * 40];
  __shared__ unsigned short b_lds[128 * 40];

  const int tid  = threadIdx.x;
  const int lane = tid & 63;
  const int wv   = tid >> 6;        // wave 0..3
  const int l15  = lane & 15;
  const int quad = lane >> 4;
  const int m0 = blockIdx.x * 128;
  const int n0 = blockIdx.y * 128;
  const int wm = (wv & 1) * 64;     // wave's 64x64 sub-tile
  const int wn = (wv >> 1) * 64;

  f32x4 acc[4][4];
  for (int i = 0; i < 4; ++i)
    for (int j = 0; j < 4; ++j)
      acc[i][j] = (f32x4){0.f, 0.f, 0.f, 0.f};

  const int ar = tid >> 2;          // staging row 0..63
  const int ac = (tid & 3) * 8;     // staging col chunk (8 elems)

  const float*          Wp  = W + (size_t)(n0 + ar) * Kd + ac;
  const float*          Wp2 = Wp + (size_t)64 * Kd;
  const float*          Af  = (const float*)Av;
  const unsigned short* Ab  = (const unsigned short*)Av;
  const size_t a_off  = (size_t)(m0 + ar) * Kd + ac;
  const size_t a_off2 = a_off + (size_t)64 * Kd;

  for (int k0 = 0; k0 < Kd; k0 += 32) {
    __syncthreads();
    if (A_IS_BF16) {
      *(uint4*)&a_lds[ar * 40 + ac]        = *(const uint4*)(Ab + a_off  + k0);
      *(uint4*)&a_lds[(ar + 64) * 40 + ac] = *(const uint4*)(Ab + a_off2 + k0);
    } else {
      cvt8_store(Af + a_off  + k0, &a_lds[ar * 40 + ac]);
      cvt8_store(Af + a_off2 + k0, &a_lds[(ar + 64) * 40 + ac]);
    }
    cvt8_store(Wp  + k0, &b_lds[ar * 40 + ac]);
    cvt8_store(Wp2 + k0, &b_lds[(ar + 64) * 40 + ac]);
    __syncthreads();

    bf16x8_t af[4], bfr[4];
    for (int i = 0; i < 4; ++i)
      af[i] = *(const bf16x8_t*)&a_lds[(wm + i * 16 + l15) * 40 + quad * 8];
    for (int j = 0; j < 4; ++j)
      bfr[j] = *(const bf16x8_t*)&b_lds[(wn + j * 16 + l15) * 40 + quad * 8];

    for (int i = 0; i < 4; ++i)
      for (int j = 0; j < 4; ++j)
        acc[i][j] = __builtin_amdgcn_mfma_f32_16x16x32_bf16(af[i], bfr[j], acc[i][j], 0, 0, 0);
  }

  // epilogue: C/D layout col = lane&15, row = quad*4 + reg  [m89]
  for (int j = 0; j < 4; ++j) {
    const int n = n0 + wn + j * 16 + l15;
    const float bv = bias[n];
    for (int i = 0; i < 4; ++i) {
      const int mbase = m0 + wm + i * 16 + quad * 4;
      for (int r = 0; r < 4; ++r) {
        const int m = mbase + r;
        const float v = acc[i][j][r] + bv;
        size_t off;
        if (OUT_QKV) {
          const int bb = m >> 11;   // m / SEQ
          const int ss = m & 2047;
          const int hh = n >> 6;    // n / DK
          const int dd = n & 63;
          off = (((size_t)bb * NHEADS + hh) * SEQ + ss) * DK + dd;
        } else {
          off = (size_t)m * N + n;
        }
        if (OUT_F32) ((float*)Cv)[off] = v;
        else         ((unsigned short*)Cv)[off] = f2bf(v);
      }
    }
  }
}

// Flash attention: grid (S/64, B*H), 256 threads. Wave wv owns 16 q-rows.
__global__ __launch_bounds__(256) void attn_kernel(
    const unsigned short* __restrict__ Q,
    const unsigned short* __restrict__ K,
    const unsigned short* __restrict__ V,
    unsigned short* __restrict__ Oattn)
{
  __shared__ unsigned short k_lds[64 * 72];    // K tile  [key][dk]
  __shared__ unsigned short vt_lds[64 * 72];   // V^T tile [dk][key]
  __shared__ unsigned short p_lds[64 * 72];    // P tile  [qrow][key]

  const int tid  = threadIdx.x;
  const int lane = tid & 63;
  const int wv   = tid >> 6;
  const int l15  = lane & 15;
  const int quad = lane >> 4;
  const int q0   = blockIdx.x * 64;
  const int bh   = blockIdx.y;
  const size_t head_off = (size_t)bh * SEQ * DK;
  const unsigned short* Qh = Q + head_off;
  const unsigned short* Kh = K + head_off;
  const unsigned short* Vh = V + head_off;

  // Q fragments: A-layout A[m=lane&15][k=quad*8+j]; kept in registers all kernel
  bf16x8_t qf[2];
  {
    const unsigned short* qrow = Qh + (size_t)(q0 + wv * 16 + l15) * DK;
    qf[0] = *(const bf16x8_t*)(qrow + quad * 8);
    qf[1] = *(const bf16x8_t*)(qrow + 32 + quad * 8);
  }

  f32x4 o_acc[4];
  for (int t = 0; t < 4; ++t) o_acc[t] = (f32x4){0.f, 0.f, 0.f, 0.f};
  float m_r[4], l_r[4];
  for (int r = 0; r < 4; ++r) { m_r[r] = -1e30f; l_r[r] = 0.f; }

  for (int kb = 0; kb < SEQ / 64; ++kb) {
    const int key0 = kb * 64;
    __syncthreads();   // protect K/Vt from previous iteration's readers

    // stage K tile, row-major stride 72
    for (int i = 0; i < 2; ++i) {
      const int c  = tid + 256 * i;
      const int kr = c >> 3;
      const int c8 = c & 7;
      uint4 d = *(const uint4*)(Kh + (size_t)(key0 + kr) * DK + c8 * 8);
      uint2* dst = (uint2*)&k_lds[kr * 72 + c8 * 8];
      dst[0] = make_uint2(d.x, d.y);
      dst[1] = make_uint2(d.z, d.w);
    }
    // stage V transposed: coalesced row reads, pack key-pairs into u32 columns
    {
      const int kp = tid >> 3;  // key pair 0..31
      const int c8 = tid & 7;
      const unsigned short* v0p = Vh + (size_t)(key0 + 2 * kp) * DK + c8 * 8;
      uint4 r0 = *(const uint4*)(v0p);
      uint4 r1 = *(const uint4*)(v0p + DK);
      const unsigned int* a = (const unsigned int*)&r0;
      const unsigned int* b = (const unsigned int*)&r1;
      for (int wd = 0; wd < 4; ++wd) {
        unsigned int av = a[wd], bv = b[wd];
        unsigned int colA = (bv << 16) | (av & 0xffffu);
        unsigned int colB = (bv & 0xffff0000u) | (av >> 16);
        const int col = c8 * 8 + wd * 2;
        *(unsigned int*)&vt_lds[col * 72 + 2 * kp]       = colA;
        *(unsigned int*)&vt_lds[(col + 1) * 72 + 2 * kp] = colB;
      }
    }
    __syncthreads();

    // S = Q K^T : B-fragment = K[key=lane&15][k=quad*8+j] (B^T contraction)
    f32x4 s_acc[4];
    for (int t = 0; t < 4; ++t) {
      bf16x8_t kf0 = lds_frag(&k_lds[(t * 16 + l15) * 72 + quad * 8]);
      bf16x8_t kf1 = lds_frag(&k_lds[(t * 16 + l15) * 72 + 32 + quad * 8]);
      f32x4 z = (f32x4){0.f, 0.f, 0.f, 0.f};
      z = __builtin_amdgcn_mfma_f32_16x16x32_bf16(qf[0], kf0, z, 0, 0, 0);
      z = __builtin_amdgcn_mfma_f32_16x16x32_bf16(qf[1], kf1, z, 0, 0, 0);
      s_acc[t] = z;
    }

    // online softmax per q-row (C-layout row = quad*4+r); 16-lane xor reductions
    for (int r = 0; r < 4; ++r) {
      float s0 = s_acc[0][r] * 0.125f;
      float s1 = s_acc[1][r] * 0.125f;
      float s2 = s_acc[2][r] * 0.125f;
      float s3 = s_acc[3][r] * 0.125f;
      float mx = fmaxf(fmaxf(s0, s1), fmaxf(s2, s3));
      for (int off = 1; off < 16; off <<= 1)
        mx = fmaxf(mx, __shfl_xor(mx, off));
      const float mnew  = fmaxf(m_r[r], mx);
      const float alpha = __expf(m_r[r] - mnew);
      m_r[r] = mnew;
      float p0 = __expf(s0 - mnew);
      float p1 = __expf(s1 - mnew);
      float p2 = __expf(s2 - mnew);
      float p3 = __expf(s3 - mnew);
      float rs = p0 + p1 + p2 + p3;
      for (int off = 1; off < 16; off <<= 1)
        rs += __shfl_xor(rs, off);
      l_r[r] = l_r[r] * alpha + rs;
      for (int t = 0; t < 4; ++t) o_acc[t][r] *= alpha;
      const int prow = (wv * 16 + quad * 4 + r) * 72 + l15;
      p_lds[prow]      = f2bf(p0);
      p_lds[prow + 16] = f2bf(p1);
      p_lds[prow + 32] = f2bf(p2);
      p_lds[prow + 48] = f2bf(p3);
    }
    // P written/read by the same wave only; drain DS queue before reading back
    asm volatile("s_waitcnt lgkmcnt(0)" ::: "memory");

    // O += P V : A-frag from p_lds, B-frag = V^T[dk=lane&15][key=quad*8+j]
    bf16x8_t pf0 = lds_frag(&p_lds[(wv * 16 + l15) * 72 + quad * 8]);
    bf16x8_t pf1 = lds_frag(&p_lds[(wv * 16 + l15) * 72 + 32 + quad * 8]);
    for (int nt = 0; nt < 4; ++nt) {
      bf16x8_t vf0 = lds_frag(&vt_lds[(nt * 16 + l15) * 72 + quad * 8]);
      bf16x8_t vf1 = lds_frag(&vt_lds[(nt * 16 + l15) * 72 + 32 + quad * 8]);
      o_acc[nt] = __builtin_amdgcn_mfma_f32_16x16x32_bf16(pf0, vf0, o_acc[nt], 0, 0, 0);
      o_acc[nt] = __builtin_amdgcn_mfma_f32_16x16x32_bf16(pf1, vf1, o_acc[nt], 0, 0, 0);
    }
  }

  // epilogue: normalize, write to [B,S,D] with D index = h*64 + dk
  const int bb = bh >> 4;
  const int hh = bh & 15;
  for (int r = 0; r < 4; ++r) {
    const float inv  = 1.0f / l_r[r];
    const int   srow = q0 + wv * 16 + quad * 4 + r;
    unsigned short* orow = Oattn + (size_t)(bb * SEQ + srow) * D_MODEL + hh * DK;
    for (int nt = 0; nt < 4; ++nt)
      orow[nt * 16 + l15] = f2bf(o_acc[nt][r] * inv);
  }
}

extern "C" void kernel_launch(void* const* d_in, const int* in_sizes, int n_in,
                              void* d_out, int out_size, void* d_ws, size_t ws_size,
                              hipStream_t stream) {
  const float* query = (const float*)d_in[0];
  const float* key   = (const float*)d_in[1];
  const float* value = (const float*)d_in[2];
  const float* Wq    = (const float*)d_in[3];
  const float* bq    = (const float*)d_in[4];
  const float* Wk    = (const float*)d_in[5];
  const float* bk    = (const float*)d_in[6];
  const float* Wv    = (const float*)d_in[7];
  const float* bv    = (const float*)d_in[8];
  const float* Wo    = (const float*)d_in[9];
  const float* bo    = (const float*)d_in[10];

  const size_t elems = (size_t)BATCH * SEQ * D_MODEL;   // 8,388,608
  unsigned short* Qws = (unsigned short*)d_ws;           // [B,H,S,dk] bf16
  unsigned short* Kws = Qws + elems;
  unsigned short* Vws = Kws + elems;
  unsigned short* Aws = Vws + elems;                     // attn out [B,S,D] bf16
  // total ws use: 64 MB

  const int M = BATCH * SEQ;   // 8192
  dim3 gg(M / 128, D_MODEL / 128), blk(256);
  gemm_bt_kernel<1, 0, 0><<<gg, blk, 0, stream>>>(query, Wq, bq, Qws, M, D_MODEL, D_MODEL);
  gemm_bt_kernel<1, 0, 0><<<gg, blk, 0, stream>>>(key,   Wk, bk, Kws, M, D_MODEL, D_MODEL);
  gemm_bt_kernel<1, 0, 0><<<gg, blk, 0, stream>>>(value, Wv, bv, Vws, M, D_MODEL, D_MODEL);
  attn_kernel<<<dim3(SEQ / 64, BATCH * NHEADS), blk, 0, stream>>>(Qws, Kws, Vws, Aws);
  gemm_bt_kernel<0, 1, 1><<<gg, blk, 0, stream>>>(Aws, Wo, bo, d_out, M, D_MODEL, D_MODEL);
}

// Round 4
// 431.560 us; speedup vs baseline: 1.3895x; 1.3895x over previous
//
#include <hip/hip_runtime.h>
#include <cstdint>
#include <cstddef>

// MultiHeadAttention B=4, S=2048, D=1024, H=16, dk=64. fp32 in/out, bf16 MFMA internals.
// Pipeline: cvt fp32->bf16 (x3 inputs, x4 weights) -> 3x gemm (m97-style glds) -> flash attn (S^T form) -> out proj.

#define BATCH   4
#define SEQ     2048
#define D_MODEL 1024
#define NHEADS  16
#define DK      64

typedef __attribute__((ext_vector_type(8))) __bf16 bf16x8_t;
typedef __attribute__((ext_vector_type(4))) float  f32x4;

__device__ inline unsigned short f2bf(float f) {
  union { float f; unsigned int i; } c; c.f = f;
  unsigned int i = c.i;
  i += 0x7FFFu + ((i >> 16) & 1u);   // RNE
  return (unsigned short)(i >> 16);
}
__device__ inline unsigned int pack2(float lo, float hi) {
  return ((unsigned int)f2bf(lo)) | (((unsigned int)f2bf(hi)) << 16);
}
__device__ inline void cvt8(const float* __restrict__ src, unsigned short* __restrict__ dst) {
  const float4 a = *(const float4*)(src);
  const float4 b = *(const float4*)(src + 4);
  uint4 r;
  r.x = pack2(a.x, a.y); r.y = pack2(a.z, a.w);
  r.z = pack2(b.x, b.y); r.w = pack2(b.z, b.w);
  *(uint4*)dst = r;
}

// async global->LDS, 16B per lane. LDS dest = wave-uniform base + lane*16B.
typedef __attribute__((address_space(3))) unsigned int lds_u32_t;
typedef const __attribute__((address_space(1))) unsigned int glb_u32_t;
__device__ inline void gld16(const unsigned short* g, unsigned short* l) {
  __builtin_amdgcn_global_load_lds((glb_u32_t*)(uintptr_t)g,
                                   (lds_u32_t*)(unsigned int)(uintptr_t)l, 16, 0, 0);
}

// ---------------- fp32 -> bf16 conversion passes ----------------
__global__ __launch_bounds__(256) void cvt3_kernel(
    const float* __restrict__ a, const float* __restrict__ b, const float* __restrict__ c,
    unsigned short* __restrict__ oa, unsigned short* __restrict__ ob, unsigned short* __restrict__ oc)
{
  const float* s = (blockIdx.y == 0) ? a : (blockIdx.y == 1) ? b : c;
  unsigned short* d = (blockIdx.y == 0) ? oa : (blockIdx.y == 1) ? ob : oc;
  const size_t i = ((size_t)blockIdx.x * 256 + threadIdx.x) * 8;
  cvt8(s + i, d + i);
}
__global__ __launch_bounds__(256) void cvt4_kernel(
    const float* __restrict__ a, const float* __restrict__ b,
    const float* __restrict__ c, const float* __restrict__ dd,
    unsigned short* __restrict__ oa, unsigned short* __restrict__ ob,
    unsigned short* __restrict__ oc, unsigned short* __restrict__ od)
{
  const float* s = (blockIdx.y == 0) ? a : (blockIdx.y == 1) ? b : (blockIdx.y == 2) ? c : dd;
  unsigned short* d = (blockIdx.y == 0) ? oa : (blockIdx.y == 1) ? ob : (blockIdx.y == 2) ? oc : od;
  const size_t i = ((size_t)blockIdx.x * 256 + threadIdx.x) * 8;
  cvt8(s + i, d + i);
}

// ---------------- GEMM: C[m][n] = (sum_k A[m][k]*W[n][k] + bias[n]) * oscale ----------------
// m97 structure: BK=32 unpadded LDS, global_load_lds 16B, chunk^row&3 swizzle (applied at
// the global source so lane-ordered DMA lands swizzled; frag reads become phase-minimal).
template <int OUT_QKV, int OUT_F32>
__global__ __launch_bounds__(256) void gemm_bt_kernel(
    const unsigned short* __restrict__ A,   // bf16 [M][K]
    const unsigned short* __restrict__ W,   // bf16 [N][K]
    const float* __restrict__ bias,         // fp32 [N]
    void* __restrict__ Cv,
    int M, int N, int Kd, float oscale)
{
  __shared__ unsigned short a_lds[128 * 32];
  __shared__ unsigned short b_lds[128 * 32];

  const int tid  = threadIdx.x;
  const int lane = tid & 63;
  const int wv   = tid >> 6;
  const int l15  = lane & 15;
  const int quad = lane >> 4;
  const int m0 = blockIdx.x * 128;
  const int n0 = blockIdx.y * 128;
  const int wm = (wv & 1) * 64;
  const int wn = (wv >> 1) * 64;

  f32x4 acc[4][4];
  for (int i = 0; i < 4; ++i)
    for (int j = 0; j < 4; ++j)
      acc[i][j] = (f32x4){0.f, 0.f, 0.f, 0.f};

  // staging: slot s=tid -> (row=s>>2, phys_chunk=s&3); semantic chunk = phys ^ (row&3)
  const int srow = tid >> 2;
  const int sch  = (tid & 3) ^ (srow & 3);
  const unsigned short* Ap0 = A + (size_t)(m0 + srow) * Kd + sch * 8;
  const unsigned short* Ap1 = A + (size_t)(m0 + 64 + srow) * Kd + sch * 8;   // (row+64)&3 unchanged
  const unsigned short* Wp0 = W + (size_t)(n0 + srow) * Kd + sch * 8;
  const unsigned short* Wp1 = W + (size_t)(n0 + 64 + srow) * Kd + sch * 8;
  unsigned short* al0 = a_lds + wv * 512;          // rows 0..63
  unsigned short* al1 = a_lds + 2048 + wv * 512;   // rows 64..127
  unsigned short* bl0 = b_lds + wv * 512;
  unsigned short* bl1 = b_lds + 2048 + wv * 512;

  const int pq = (quad ^ (l15 & 3)) * 8;           // swizzled frag chunk offset (hw)

  for (int k0 = 0; k0 < Kd; k0 += 32) {
    __syncthreads();
    gld16(Ap0 + k0, al0);
    gld16(Ap1 + k0, al1);
    gld16(Wp0 + k0, bl0);
    gld16(Wp1 + k0, bl1);
    __syncthreads();

    bf16x8_t af[4], bfr[4];
#pragma unroll
    for (int i = 0; i < 4; ++i)
      af[i] = *(const bf16x8_t*)&a_lds[(wm + i * 16 + l15) * 32 + pq];
#pragma unroll
    for (int j = 0; j < 4; ++j)
      bfr[j] = *(const bf16x8_t*)&b_lds[(wn + j * 16 + l15) * 32 + pq];

#pragma unroll
    for (int i = 0; i < 4; ++i)
#pragma unroll
      for (int j = 0; j < 4; ++j)
        acc[i][j] = __builtin_amdgcn_mfma_f32_16x16x32_bf16(af[i], bfr[j], acc[i][j], 0, 0, 0);
  }

  // epilogue: C/D layout col = lane&15, row = quad*4 + reg  [m89]
  for (int j = 0; j < 4; ++j) {
    const int n = n0 + wn + j * 16 + l15;
    const float bv = bias[n];
    for (int i = 0; i < 4; ++i) {
      const int mbase = m0 + wm + i * 16 + quad * 4;
      for (int r = 0; r < 4; ++r) {
        const int m = mbase + r;
        const float v = (acc[i][j][r] + bv) * oscale;
        size_t off;
        if (OUT_QKV) {
          const int bb = m >> 11;
          const int ss = m & 2047;
          const int hh = n >> 6;
          const int dd = n & 63;
          off = (((size_t)bb * NHEADS + hh) * SEQ + ss) * DK + dd;
        } else {
          off = (size_t)m * N + n;
        }
        if (OUT_F32) ((float*)Cv)[off] = v;
        else         ((unsigned short*)Cv)[off] = f2bf(v);
      }
    }
  }
}

// ---------------- Flash attention, S^T formulation ----------------
// grid (S/64, B*H), 256 thr. Wave wv owns q-rows q0+wv*16+l15 (q = lane&15 per lane).
// S^T = K*Q^T  (A=K rows, B=Q rows; C: row=key, col=q) -> per-lane softmax, 2 shuffles.
// O^T = V^T*P^T (A=V^T rows, B=P rows; C: row=d, col=q).
// All LDS tiles: stride 64 hw, XOR swizzle phys_chunk = chunk ^ (row&7) ^ (row>>3).
__global__ __launch_bounds__(256) void attn_kernel(
    const unsigned short* __restrict__ Q,   // [B,H,S,dk] bf16, pre-scaled by 1/8
    const unsigned short* __restrict__ K,
    const unsigned short* __restrict__ V,
    unsigned short* __restrict__ Oattn)     // [B,S,D] bf16
{
  __shared__ unsigned short k_sw[64 * 64];
  __shared__ unsigned short vt_sw[64 * 64];
  __shared__ unsigned short pt_sw[4 * 16 * 64];

  const int tid  = threadIdx.x;
  const int lane = tid & 63;
  const int wv   = tid >> 6;
  const int l15  = lane & 15;
  const int quad = lane >> 4;
  const int q0   = blockIdx.x * 64;
  const int bh   = blockIdx.y;
  const size_t hoff = (size_t)bh * SEQ * DK;
  const unsigned short* Qh = Q + hoff;
  const unsigned short* Kh = K + hoff;
  const unsigned short* Vh = V + hoff;

  // Q fragments (B-operand = Q rows), in registers for the whole kernel
  bf16x8_t qf0, qf1;
  {
    const unsigned short* qr = Qh + (size_t)(q0 + wv * 16 + l15) * DK;
    qf0 = *(const bf16x8_t*)(qr + quad * 8);
    qf1 = *(const bf16x8_t*)(qr + 32 + quad * 8);
  }

  f32x4 o[4];
#pragma unroll
  for (int t = 0; t < 4; ++t) o[t] = (f32x4){0.f, 0.f, 0.f, 0.f};
  float mval = -1e30f, lval = 0.f;

  const int kr = tid >> 3;        // 0..31
  const int c8 = tid & 7;
  const int swz_l15 = (l15 & 7) ^ (l15 >> 3);      // pt rows are 0..15
  unsigned short* pt_base = pt_sw + wv * 1024;     // per-wave 16x64 region

  for (int kb = 0; kb < SEQ / 64; ++kb) {
    const int key0 = kb * 64;
    __syncthreads();

    // --- stage K tile [key][dk], swizzled ---
    {
      uint4 d0 = *(const uint4*)(Kh + (size_t)(key0 + kr) * DK + c8 * 8);
      uint4 d1 = *(const uint4*)(Kh + (size_t)(key0 + kr + 32) * DK + c8 * 8);
      const int r0 = kr, r1 = kr + 32;
      *(uint4*)&k_sw[r0 * 64 + ((c8 ^ ((r0 & 7) ^ (r0 >> 3))) << 3)] = d0;
      *(uint4*)&k_sw[r1 * 64 + ((c8 ^ ((r1 & 7) ^ (r1 >> 3))) << 3)] = d1;
    }
    // --- stage V^T tile [dk][key], swizzled; coalesced row reads, pack key pairs ---
    {
      const unsigned short* vp = Vh + (size_t)(key0 + 2 * kr) * DK + c8 * 8;
      uint4 ra = *(const uint4*)vp;
      uint4 rb = *(const uint4*)(vp + DK);
      const unsigned int* pa = (const unsigned int*)&ra;
      const unsigned int* pb = (const unsigned int*)&rb;
      const int kchunk = kr >> 2;          // (2kr)>>3
      const int klo    = (2 * kr) & 7;
#pragma unroll
      for (int wd = 0; wd < 4; ++wd) {
        unsigned int av = pa[wd], bv = pb[wd];
        unsigned int colA = (bv << 16) | (av & 0xffffu);
        unsigned int colB = (bv & 0xffff0000u) | (av >> 16);
        const int d0 = c8 * 8 + wd * 2, d1 = d0 + 1;
        *(unsigned int*)&vt_sw[d0 * 64 + ((kchunk ^ ((d0 & 7) ^ (d0 >> 3))) << 3) + klo] = colA;
        *(unsigned int*)&vt_sw[d1 * 64 + ((kchunk ^ ((d1 & 7) ^ (d1 >> 3))) << 3) + klo] = colB;
      }
    }
    __syncthreads();

    // --- S^T = K·Q^T ---
    f32x4 s[4];
#pragma unroll
    for (int t = 0; t < 4; ++t) {
      const int row = t * 16 + l15;
      const int sw  = (row & 7) ^ (row >> 3);
      bf16x8_t kf0 = *(const bf16x8_t*)&k_sw[row * 64 + ((quad ^ sw) << 3)];
      bf16x8_t kf1 = *(const bf16x8_t*)&k_sw[row * 64 + (((quad | 4) ^ sw) << 3)];
      f32x4 z = (f32x4){0.f, 0.f, 0.f, 0.f};
      z = __builtin_amdgcn_mfma_f32_16x16x32_bf16(kf0, qf0, z, 0, 0, 0);
      z = __builtin_amdgcn_mfma_f32_16x16x32_bf16(kf1, qf1, z, 0, 0, 0);
      s[t] = z;
    }

    // --- online softmax: per-lane over 16 vals + 2 cross-quad shuffles ---
    float mx = s[0][0];
#pragma unroll
    for (int t = 0; t < 4; ++t)
#pragma unroll
      for (int r = 0; r < 4; ++r) mx = fmaxf(mx, s[t][r]);
    mx = fmaxf(mx, __shfl_xor(mx, 16));
    mx = fmaxf(mx, __shfl_xor(mx, 32));
    const float mnew  = fmaxf(mval, mx);
    const float alpha = __expf(mval - mnew);
    mval = mnew;
    float rs = 0.f;
    float p[4][4];
#pragma unroll
    for (int t = 0; t < 4; ++t)
#pragma unroll
      for (int r = 0; r < 4; ++r) { p[t][r] = __expf(s[t][r] - mnew); rs += p[t][r]; }
    rs += __shfl_xor(rs, 16);
    rs += __shfl_xor(rs, 32);
    lval = lval * alpha + rs;
#pragma unroll
    for (int t = 0; t < 4; ++t) o[t] *= alpha;

    // --- P -> LDS as rows [q][key], packed b64 stores ---
#pragma unroll
    for (int t = 0; t < 4; ++t) {
      const int chunk = 2 * t + (quad >> 1);
      unsigned short* dst = pt_base + l15 * 64 + ((chunk ^ swz_l15) << 3) + (quad & 1) * 4;
      *(uint2*)dst = make_uint2(pack2(p[t][0], p[t][1]), pack2(p[t][2], p[t][3]));
    }
    // same-wave write->read: drain DS queue, no barrier needed
    asm volatile("s_waitcnt lgkmcnt(0)" ::: "memory");

    bf16x8_t pf0 = *(const bf16x8_t*)(pt_base + l15 * 64 + ((quad ^ swz_l15) << 3));
    bf16x8_t pf1 = *(const bf16x8_t*)(pt_base + l15 * 64 + (((quad | 4) ^ swz_l15) << 3));

    // --- O^T += V^T · P^T ---
#pragma unroll
    for (int nt = 0; nt < 4; ++nt) {
      const int row = nt * 16 + l15;
      const int sw  = (row & 7) ^ (row >> 3);
      bf16x8_t vf0 = *(const bf16x8_t*)&vt_sw[row * 64 + ((quad ^ sw) << 3)];
      bf16x8_t vf1 = *(const bf16x8_t*)&vt_sw[row * 64 + (((quad | 4) ^ sw) << 3)];
      o[nt] = __builtin_amdgcn_mfma_f32_16x16x32_bf16(vf0, pf0, o[nt], 0, 0, 0);
      o[nt] = __builtin_amdgcn_mfma_f32_16x16x32_bf16(vf1, pf1, o[nt], 0, 0, 0);
    }
  }

  // epilogue: lane owns q = q0+wv*16+l15, d = nt*16 + quad*4 + r
  const int bb = bh >> 4, hh = bh & 15;
  const float inv = 1.0f / lval;
  unsigned short* orow = Oattn + (size_t)(bb * SEQ + q0 + wv * 16 + l15) * D_MODEL + hh * DK + quad * 4;
#pragma unroll
  for (int nt = 0; nt < 4; ++nt) {
    f32x4 v = o[nt];
    *(uint2*)(orow + nt * 16) = make_uint2(pack2(v[0] * inv, v[1] * inv),
                                           pack2(v[2] * inv, v[3] * inv));
  }
}

extern "C" void kernel_launch(void* const* d_in, const int* in_sizes, int n_in,
                              void* d_out, int out_size, void* d_ws, size_t ws_size,
                              hipStream_t stream) {
  const float* query = (const float*)d_in[0];
  const float* key   = (const float*)d_in[1];
  const float* value = (const float*)d_in[2];
  const float* Wq    = (const float*)d_in[3];
  const float* bq    = (const float*)d_in[4];
  const float* Wk    = (const float*)d_in[5];
  const float* bk    = (const float*)d_in[6];
  const float* Wv    = (const float*)d_in[7];
  const float* bv    = (const float*)d_in[8];
  const float* Wo    = (const float*)d_in[9];
  const float* bo    = (const float*)d_in[10];

  const size_t E  = (size_t)BATCH * SEQ * D_MODEL;   // 8,388,608
  const size_t WE = (size_t)D_MODEL * D_MODEL;       // 1,048,576
  unsigned short* ws  = (unsigned short*)d_ws;
  unsigned short* Qws = ws;                          // [B,H,S,dk] bf16 (Q pre-scaled 1/8)
  unsigned short* Kws = ws + E;
  unsigned short* Vws = ws + 2 * E;
  unsigned short* qb  = ws + 3 * E;                  // bf16 input copies
  unsigned short* kb  = ws + 4 * E;
  unsigned short* vb  = ws + 5 * E;
  unsigned short* wqb = ws + 6 * E;
  unsigned short* wkb = wqb + WE;
  unsigned short* wvb = wqb + 2 * WE;
  unsigned short* wob = wqb + 3 * WE;
  unsigned short* Aws = qb;                          // alias: qb dead after Q-GEMM
  // total ws use: (6E + 4WE)*2 = 104 MB

  const int M = BATCH * SEQ;   // 8192
  cvt3_kernel<<<dim3(E / 2048, 3), 256, 0, stream>>>(query, key, value, qb, kb, vb);
  cvt4_kernel<<<dim3(WE / 2048, 4), 256, 0, stream>>>(Wq, Wk, Wv, Wo, wqb, wkb, wvb, wob);

  dim3 gg(M / 128, D_MODEL / 128), blk(256);
  gemm_bt_kernel<1, 0><<<gg, blk, 0, stream>>>(qb, wqb, bq, Qws, M, D_MODEL, D_MODEL, 0.125f);
  gemm_bt_kernel<1, 0><<<gg, blk, 0, stream>>>(kb, wkb, bk, Kws, M, D_MODEL, D_MODEL, 1.0f);
  gemm_bt_kernel<1, 0><<<gg, blk, 0, stream>>>(vb, wvb, bv, Vws, M, D_MODEL, D_MODEL, 1.0f);
  attn_kernel<<<dim3(SEQ / 64, BATCH * NHEADS), blk, 0, stream>>>(Qws, Kws, Vws, Aws);
  gemm_bt_kernel<0, 1><<<gg, blk, 0, stream>>>(Aws, wob, bo, d_out, M, D_MODEL, D_MODEL, 1.0f);
}

// Round 5
// 402.968 us; speedup vs baseline: 1.4881x; 1.0710x over previous
//
#include <hip/hip_runtime.h>
#include <hip/hip_bf16.h>
#include <cstdint>
#include <cstddef>

// MultiHeadAttention B=4, S=2048, D=1024, H=16, dk=64. fp32 in/out, bf16 MFMA internals.
// cvt fp32->bf16 -> fused QKV gemm (V written transposed [B,H,dk,S]) -> flash attn (DMA-staged) -> out proj.

#define BATCH   4
#define SEQ     2048
#define D_MODEL 1024
#define NHEADS  16
#define DK      64

typedef __attribute__((ext_vector_type(8))) __bf16 bf16x8_t;
typedef __attribute__((ext_vector_type(4))) float  f32x4;

// HW packed fp32->bf16 (v_cvt_pk_bf16_f32 on gfx950)
__device__ inline unsigned int pack2(float lo, float hi) {
  __hip_bfloat162 h = __float22bfloat162_rn(make_float2(lo, hi));
  union { __hip_bfloat162 h; unsigned int u; } c; c.h = h; return c.u;
}
__device__ inline unsigned short f2bf(float f) { return (unsigned short)pack2(f, f); }

#if __has_builtin(__builtin_amdgcn_exp2f)
__device__ inline float fexp2(float x) { return __builtin_amdgcn_exp2f(x); }
#else
__device__ inline float fexp2(float x) { return __expf(x * 0.6931471805599453f); }
#endif

__device__ inline void cvt8(const float* __restrict__ s, unsigned short* __restrict__ d) {
  const float4 a = *(const float4*)s;
  const float4 b = *(const float4*)(s + 4);
  uint4 r;
  r.x = pack2(a.x, a.y); r.y = pack2(a.z, a.w);
  r.z = pack2(b.x, b.y); r.w = pack2(b.z, b.w);
  *(uint4*)d = r;
}

// async global->LDS, 16B/lane; LDS dest = wave-uniform base + lane*16B
typedef __attribute__((address_space(3))) unsigned int lds_u32_t;
typedef const __attribute__((address_space(1))) unsigned int glb_u32_t;
__device__ inline void gld16(const unsigned short* g, unsigned short* l) {
  __builtin_amdgcn_global_load_lds((glb_u32_t*)(uintptr_t)g,
                                   (lds_u32_t*)(unsigned int)(uintptr_t)l, 16, 0, 0);
}

// ---------------- fp32 -> bf16 conversion ----------------
__global__ __launch_bounds__(256) void cvt3_kernel(
    const float* __restrict__ a, const float* __restrict__ b, const float* __restrict__ c,
    unsigned short* __restrict__ oa, unsigned short* __restrict__ ob, unsigned short* __restrict__ oc)
{
  const float* s = (blockIdx.y == 0) ? a : (blockIdx.y == 1) ? b : c;
  unsigned short* d = (blockIdx.y == 0) ? oa : (blockIdx.y == 1) ? ob : oc;
  const size_t i = ((size_t)blockIdx.x * 256 + threadIdx.x) * 8;
  cvt8(s + i, d + i);
}
__global__ __launch_bounds__(256) void cvt4_kernel(
    const float* __restrict__ a, const float* __restrict__ b,
    const float* __restrict__ c, const float* __restrict__ dd,
    unsigned short* __restrict__ oa, unsigned short* __restrict__ ob,
    unsigned short* __restrict__ oc, unsigned short* __restrict__ od)
{
  const float* s = (blockIdx.y == 0) ? a : (blockIdx.y == 1) ? b : (blockIdx.y == 2) ? c : dd;
  unsigned short* d = (blockIdx.y == 0) ? oa : (blockIdx.y == 1) ? ob : (blockIdx.y == 2) ? oc : od;
  const size_t i = ((size_t)blockIdx.x * 256 + threadIdx.x) * 8;
  cvt8(s + i, d + i);
}

// ---------------- shared GEMM core: acc += A[128 rows @m0] * W[128 rows @n0]^T ----------------
// m97 structure: BK=32 unpadded LDS, global_load_lds 16B, chunk^(row&3) source-side swizzle.
__device__ inline void gemm_core(const unsigned short* __restrict__ A,
                                 const unsigned short* __restrict__ W,
                                 unsigned short* a_lds, unsigned short* b_lds,
                                 int m0, int n0, f32x4 (&acc)[4][4])
{
  const int tid  = threadIdx.x;
  const int lane = tid & 63;
  const int wv   = tid >> 6;
  const int l15  = lane & 15;
  const int quad = lane >> 4;
  const int wm = (wv & 1) * 64;
  const int wn = (wv >> 1) * 64;

  const int srow = tid >> 2;
  const int sch  = (tid & 3) ^ (srow & 3);
  const unsigned short* Ap0 = A + (size_t)(m0 + srow) * D_MODEL + sch * 8;
  const unsigned short* Ap1 = Ap0 + (size_t)64 * D_MODEL;
  const unsigned short* Wp0 = W + (size_t)(n0 + srow) * D_MODEL + sch * 8;
  const unsigned short* Wp1 = Wp0 + (size_t)64 * D_MODEL;
  unsigned short* al0 = a_lds + wv * 512;
  unsigned short* al1 = a_lds + 2048 + wv * 512;
  unsigned short* bl0 = b_lds + wv * 512;
  unsigned short* bl1 = b_lds + 2048 + wv * 512;

  const int pq = (quad ^ (l15 & 3)) * 8;

  for (int k0 = 0; k0 < D_MODEL; k0 += 32) {
    __syncthreads();
    gld16(Ap0 + k0, al0);
    gld16(Ap1 + k0, al1);
    gld16(Wp0 + k0, bl0);
    gld16(Wp1 + k0, bl1);
    __syncthreads();

    bf16x8_t af[4], bfr[4];
#pragma unroll
    for (int i = 0; i < 4; ++i)
      af[i] = *(const bf16x8_t*)&a_lds[(wm + i * 16 + l15) * 32 + pq];
#pragma unroll
    for (int j = 0; j < 4; ++j)
      bfr[j] = *(const bf16x8_t*)&b_lds[(wn + j * 16 + l15) * 32 + pq];

#pragma unroll
    for (int i = 0; i < 4; ++i)
#pragma unroll
      for (int j = 0; j < 4; ++j)
        acc[i][j] = __builtin_amdgcn_mfma_f32_16x16x32_bf16(af[i], bfr[j], acc[i][j], 0, 0, 0);
  }
}

// ---------------- fused QKV projection ----------------
// grid (M/128, N/128, 3). z=0: Q (scaled log2e/8, scatter [B,H,S,dk]); z=1: K (scatter);
// z=2: V written TRANSPOSED [B,H,dk,S].
__global__ __launch_bounds__(256) void qkv_kernel(
    const unsigned short* __restrict__ qb, const unsigned short* __restrict__ kb,
    const unsigned short* __restrict__ vb,
    const unsigned short* __restrict__ wq, const unsigned short* __restrict__ wk,
    const unsigned short* __restrict__ wvp,
    const float* __restrict__ bq, const float* __restrict__ bk, const float* __restrict__ bv,
    unsigned short* __restrict__ Qws, unsigned short* __restrict__ Kws,
    unsigned short* __restrict__ Vws)
{
  __shared__ unsigned short a_lds[128 * 32];
  __shared__ unsigned short b_lds[128 * 32];

  const int z = blockIdx.z;
  const unsigned short* A = (z == 0) ? qb : (z == 1) ? kb : vb;
  const unsigned short* W = (z == 0) ? wq : (z == 1) ? wk : wvp;
  const float* bias       = (z == 0) ? bq : (z == 1) ? bk : bv;
  unsigned short* C       = (z == 0) ? Qws : (z == 1) ? Kws : Vws;
  const int m0 = blockIdx.x * 128;
  const int n0 = blockIdx.y * 128;

  f32x4 acc[4][4];
#pragma unroll
  for (int i = 0; i < 4; ++i)
#pragma unroll
    for (int j = 0; j < 4; ++j)
      acc[i][j] = (f32x4){0.f, 0.f, 0.f, 0.f};

  gemm_core(A, W, a_lds, b_lds, m0, n0, acc);

  const int tid  = threadIdx.x;
  const int lane = tid & 63;
  const int wv   = tid >> 6;
  const int l15  = lane & 15;
  const int quad = lane >> 4;
  const int wm = (wv & 1) * 64;
  const int wn = (wv >> 1) * 64;
  // C/D layout: col = lane&15, row = quad*4 + reg  [m89]
  if (z == 2) {
    // V^T: off = ((bb*H+hh)*DK+dd)*SEQ + ss; 4 consecutive ss per lane -> uint2
    for (int j = 0; j < 4; ++j) {
      const int n = n0 + wn + j * 16 + l15;
      const int hh = n >> 6, dd = n & 63;
      const float bvl = bias[n];
      for (int i = 0; i < 4; ++i) {
        const int mbase = m0 + wm + i * 16 + quad * 4;
        const int bb = mbase >> 11, ss = mbase & 2047;
        uint2 w2 = make_uint2(pack2(acc[i][j][0] + bvl, acc[i][j][1] + bvl),
                              pack2(acc[i][j][2] + bvl, acc[i][j][3] + bvl));
        *(uint2*)(C + (((size_t)bb * NHEADS + hh) * DK + dd) * SEQ + ss) = w2;
      }
    }
  } else {
    const float oscale = (z == 0) ? 0.18033688011112042f : 1.0f;  // log2(e)/8 for Q
    for (int j = 0; j < 4; ++j) {
      const int n = n0 + wn + j * 16 + l15;
      const int hh = n >> 6, dd = n & 63;
      const float bvl = bias[n];
      for (int i = 0; i < 4; ++i) {
        const int mbase = m0 + wm + i * 16 + quad * 4;
        const int bb = mbase >> 11, ss = mbase & 2047;
        unsigned short* dst = C + (((size_t)bb * NHEADS + hh) * SEQ + ss) * DK + dd;
        for (int r = 0; r < 4; ++r)
          dst[(size_t)r * DK] = f2bf((acc[i][j][r] + bvl) * oscale);
      }
    }
  }
}

// ---------------- output projection (bf16 A, fp32 out) ----------------
__global__ __launch_bounds__(256) void outproj_kernel(
    const unsigned short* __restrict__ A, const unsigned short* __restrict__ W,
    const float* __restrict__ bias, float* __restrict__ C)
{
  __shared__ unsigned short a_lds[128 * 32];
  __shared__ unsigned short b_lds[128 * 32];
  const int m0 = blockIdx.x * 128;
  const int n0 = blockIdx.y * 128;

  f32x4 acc[4][4];
#pragma unroll
  for (int i = 0; i < 4; ++i)
#pragma unroll
    for (int j = 0; j < 4; ++j)
      acc[i][j] = (f32x4){0.f, 0.f, 0.f, 0.f};

  gemm_core(A, W, a_lds, b_lds, m0, n0, acc);

  const int tid  = threadIdx.x;
  const int lane = tid & 63;
  const int wv   = tid >> 6;
  const int l15  = lane & 15;
  const int quad = lane >> 4;
  const int wm = (wv & 1) * 64;
  const int wn = (wv >> 1) * 64;
  for (int j = 0; j < 4; ++j) {
    const int n = n0 + wn + j * 16 + l15;
    const float bvl = bias[n];
    for (int i = 0; i < 4; ++i) {
      const int mbase = m0 + wm + i * 16 + quad * 4;
      for (int r = 0; r < 4; ++r)
        C[(size_t)(mbase + r) * D_MODEL + n] = acc[i][j][r] + bvl;
    }
  }
}

// ---------------- Flash attention, S^T form, DMA-staged K and V^T ----------------
// grid (B*H, S/64), 256 thr. Wave wv owns q-rows q0+wv*16+l15.
// S^T = K*Q^T; per-lane softmax (base-2; Q pre-scaled by log2e/8); O^T = V^T*P^T.
// LDS tiles stride 64, source-side XOR swizzle chunk^(row&7)^(row>>3).
__global__ __launch_bounds__(256) void attn_kernel(
    const unsigned short* __restrict__ Q,    // [B,H,S,dk]
    const unsigned short* __restrict__ K,    // [B,H,S,dk]
    const unsigned short* __restrict__ Vt,   // [B,H,dk,S]  (pre-transposed)
    unsigned short* __restrict__ Oattn)      // [B,S,D]
{
  __shared__ unsigned short k_sw[64 * 64];
  __shared__ unsigned short vt_sw[64 * 64];
  __shared__ unsigned short pt_sw[4 * 16 * 64];

  const int tid  = threadIdx.x;
  const int lane = tid & 63;
  const int wv   = tid >> 6;
  const int l15  = lane & 15;
  const int quad = lane >> 4;
  const int bh   = blockIdx.x;            // bh-major: XCD = bh%8 -> K/V L2 locality
  const int q0   = blockIdx.y * 64;
  const size_t hoff = (size_t)bh * SEQ * DK;
  const unsigned short* Qh  = Q  + hoff;
  const unsigned short* Kh  = K  + hoff;
  const unsigned short* Vth = Vt + hoff;

  bf16x8_t qf0, qf1;
  {
    const unsigned short* qr = Qh + (size_t)(q0 + wv * 16 + l15) * DK;
    qf0 = *(const bf16x8_t*)(qr + quad * 8);
    qf1 = *(const bf16x8_t*)(qr + 32 + quad * 8);
  }

  f32x4 o[4];
#pragma unroll
  for (int t = 0; t < 4; ++t) o[t] = (f32x4){0.f, 0.f, 0.f, 0.f};
  float mval = -1e30f, lval = 0.f;

  // DMA staging: wave wv covers tile rows [wv*16, wv*16+16) in two 8-row calls.
  const int sr = lane >> 3;               // 0..7
  const int pc = lane & 7;                // phys chunk
  const int r0 = wv * 16 + sr;
  const int r1 = r0 + 8;
  const int sem0 = pc ^ (r0 & 7) ^ (r0 >> 3);
  const int sem1 = pc ^ (r1 & 7) ^ (r1 >> 3);
  const unsigned short* Ks0 = Kh  + (size_t)r0 * DK  + sem0 * 8;   // + key0*DK per iter
  const unsigned short* Ks1 = Kh  + (size_t)r1 * DK  + sem1 * 8;
  const unsigned short* Vs0 = Vth + (size_t)r0 * SEQ + sem0 * 8;   // + key0 per iter
  const unsigned short* Vs1 = Vth + (size_t)r1 * SEQ + sem1 * 8;
  unsigned short* kd0 = k_sw  + wv * 1024;
  unsigned short* kd1 = k_sw  + wv * 1024 + 512;
  unsigned short* vd0 = vt_sw + wv * 1024;
  unsigned short* vd1 = vt_sw + wv * 1024 + 512;

  const int swz_l15 = (l15 & 7) ^ (l15 >> 3);
  unsigned short* pt_base = pt_sw + wv * 1024;

  for (int kb = 0; kb < SEQ / 64; ++kb) {
    const int key0 = kb * 64;
    __syncthreads();
    gld16(Ks0 + (size_t)key0 * DK, kd0);
    gld16(Ks1 + (size_t)key0 * DK, kd1);
    gld16(Vs0 + key0, vd0);
    gld16(Vs1 + key0, vd1);
    __syncthreads();

    // S^T = K·Q^T
    f32x4 s[4];
#pragma unroll
    for (int t = 0; t < 4; ++t) {
      const int row = t * 16 + l15;
      const int sw  = (row & 7) ^ (row >> 3);
      bf16x8_t kf0 = *(const bf16x8_t*)&k_sw[row * 64 + ((quad ^ sw) << 3)];
      bf16x8_t kf1 = *(const bf16x8_t*)&k_sw[row * 64 + (((quad | 4) ^ sw) << 3)];
      f32x4 z = (f32x4){0.f, 0.f, 0.f, 0.f};
      z = __builtin_amdgcn_mfma_f32_16x16x32_bf16(kf0, qf0, z, 0, 0, 0);
      z = __builtin_amdgcn_mfma_f32_16x16x32_bf16(kf1, qf1, z, 0, 0, 0);
      s[t] = z;
    }

    // online softmax, base-2 (scale folded into Q)
    float mx = s[0][0];
#pragma unroll
    for (int t = 0; t < 4; ++t)
#pragma unroll
      for (int r = 0; r < 4; ++r) mx = fmaxf(mx, s[t][r]);
    mx = fmaxf(mx, __shfl_xor(mx, 16));
    mx = fmaxf(mx, __shfl_xor(mx, 32));
    const float mnew  = fmaxf(mval, mx);
    const float alpha = fexp2(mval - mnew);
    mval = mnew;
    float rs = 0.f;
    float p[4][4];
#pragma unroll
    for (int t = 0; t < 4; ++t)
#pragma unroll
      for (int r = 0; r < 4; ++r) { p[t][r] = fexp2(s[t][r] - mnew); rs += p[t][r]; }
    rs += __shfl_xor(rs, 16);
    rs += __shfl_xor(rs, 32);
    lval = lval * alpha + rs;
#pragma unroll
    for (int t = 0; t < 4; ++t) o[t] *= alpha;

    // P -> LDS rows [q][key], b64 packed stores (HW cvt_pk)
#pragma unroll
    for (int t = 0; t < 4; ++t) {
      const int chunk = 2 * t + (quad >> 1);
      unsigned short* dst = pt_base + l15 * 64 + ((chunk ^ swz_l15) << 3) + (quad & 1) * 4;
      *(uint2*)dst = make_uint2(pack2(p[t][0], p[t][1]), pack2(p[t][2], p[t][3]));
    }
    asm volatile("s_waitcnt lgkmcnt(0)" ::: "memory");   // same-wave write->read

    bf16x8_t pf0 = *(const bf16x8_t*)(pt_base + l15 * 64 + ((quad ^ swz_l15) << 3));
    bf16x8_t pf1 = *(const bf16x8_t*)(pt_base + l15 * 64 + (((quad | 4) ^ swz_l15) << 3));

    // O^T += V^T · P^T
#pragma unroll
    for (int nt = 0; nt < 4; ++nt) {
      const int row = nt * 16 + l15;
      const int sw  = (row & 7) ^ (row >> 3);
      bf16x8_t vf0 = *(const bf16x8_t*)&vt_sw[row * 64 + ((quad ^ sw) << 3)];
      bf16x8_t vf1 = *(const bf16x8_t*)&vt_sw[row * 64 + (((quad | 4) ^ sw) << 3)];
      o[nt] = __builtin_amdgcn_mfma_f32_16x16x32_bf16(vf0, pf0, o[nt], 0, 0, 0);
      o[nt] = __builtin_amdgcn_mfma_f32_16x16x32_bf16(vf1, pf1, o[nt], 0, 0, 0);
    }
  }

  // epilogue: lane owns q = q0+wv*16+l15, d = nt*16 + quad*4 + r
  const int bb = bh >> 4, hh = bh & 15;
  const float inv = 1.0f / lval;
  unsigned short* orow = Oattn + (size_t)(bb * SEQ + q0 + wv * 16 + l15) * D_MODEL + hh * DK + quad * 4;
#pragma unroll
  for (int nt = 0; nt < 4; ++nt) {
    f32x4 v = o[nt];
    *(uint2*)(orow + nt * 16) = make_uint2(pack2(v[0] * inv, v[1] * inv),
                                           pack2(v[2] * inv, v[3] * inv));
  }
}

extern "C" void kernel_launch(void* const* d_in, const int* in_sizes, int n_in,
                              void* d_out, int out_size, void* d_ws, size_t ws_size,
                              hipStream_t stream) {
  const float* query = (const float*)d_in[0];
  const float* key   = (const float*)d_in[1];
  const float* value = (const float*)d_in[2];
  const float* Wq    = (const float*)d_in[3];
  const float* bq    = (const float*)d_in[4];
  const float* Wk    = (const float*)d_in[5];
  const float* bk    = (const float*)d_in[6];
  const float* Wv    = (const float*)d_in[7];
  const float* bv    = (const float*)d_in[8];
  const float* Wo    = (const float*)d_in[9];
  const float* bo    = (const float*)d_in[10];

  const size_t E  = (size_t)BATCH * SEQ * D_MODEL;   // 8,388,608
  const size_t WE = (size_t)D_MODEL * D_MODEL;       // 1,048,576
  unsigned short* ws  = (unsigned short*)d_ws;
  unsigned short* Qws = ws;                          // [B,H,S,dk], pre-scaled log2e/8
  unsigned short* Kws = ws + E;
  unsigned short* Vws = ws + 2 * E;                  // [B,H,dk,S] transposed
  unsigned short* qb  = ws + 3 * E;
  unsigned short* kb  = ws + 4 * E;
  unsigned short* vb  = ws + 5 * E;
  unsigned short* wqb = ws + 6 * E;
  unsigned short* wkb = wqb + WE;
  unsigned short* wvb = wqb + 2 * WE;
  unsigned short* wob = wqb + 3 * WE;
  unsigned short* Aws = qb;                          // alias: qb dead after QKV GEMM

  cvt3_kernel<<<dim3(E / 2048, 3), 256, 0, stream>>>(query, key, value, qb, kb, vb);
  cvt4_kernel<<<dim3(WE / 2048, 4), 256, 0, stream>>>(Wq, Wk, Wv, Wo, wqb, wkb, wvb, wob);

  qkv_kernel<<<dim3(BATCH * SEQ / 128, D_MODEL / 128, 3), 256, 0, stream>>>(
      qb, kb, vb, wqb, wkb, wvb, bq, bk, bv, Qws, Kws, Vws);
  attn_kernel<<<dim3(BATCH * NHEADS, SEQ / 64), 256, 0, stream>>>(Qws, Kws, Vws, Aws);
  outproj_kernel<<<dim3(BATCH * SEQ / 128, D_MODEL / 128), 256, 0, stream>>>(
      Aws, wob, bo, (float*)d_out);
}